// Round 18
// baseline (246.656 us; speedup 1.0000x reference)
//
#include <hip/hip_runtime.h>
#include <math.h>

#define NN 50000
#define MM 4
#define EE 400000
#define BB 64
#define NROWS (NN*MM)           // 200000
#define NBLK_SCAN 98            // ceil(50000/512)

typedef __attribute__((ext_vector_type(8))) short bf16x8;
typedef __attribute__((ext_vector_type(4))) float f32x4;

struct f8 { float4 lo, hi; };

// ---------- helpers ----------

__device__ __forceinline__ unsigned enc_f(float f) {
  unsigned u = __float_as_uint(f);
  return (u & 0x80000000u) ? ~u : (u | 0x80000000u);
}
__device__ __forceinline__ float dec_f(unsigned u) {
  return (u & 0x80000000u) ? __uint_as_float(u ^ 0x80000000u) : __uint_as_float(~u);
}

__device__ __forceinline__ unsigned short bf16rn(float f) {
  unsigned u = __float_as_uint(f);
  return (unsigned short)((u + 0x7FFFu + ((u >> 16) & 1u)) >> 16);
}
__device__ __forceinline__ float bf2f(unsigned short h) {
  return __uint_as_float(((unsigned)h) << 16);
}

// swizzled scalar column within a 64-short row: 16B slot ^= (row & 7)
__device__ __forceinline__ int swzc(int row, int col) {
  return ((((col >> 3) ^ (row & 7)) << 3)) | (col & 7);
}

__device__ __forceinline__ f8 zero8() {
  f8 r; r.lo = make_float4(0.f,0.f,0.f,0.f); r.hi = r.lo; return r;
}
__device__ __forceinline__ void add8(f8& a, const f8& b) {
  a.lo.x += b.lo.x; a.lo.y += b.lo.y; a.lo.z += b.lo.z; a.lo.w += b.lo.w;
  a.hi.x += b.hi.x; a.hi.y += b.hi.y; a.hi.z += b.hi.z; a.hi.w += b.hi.w;
}
__device__ __forceinline__ f8 b2f8(bf16x8 v) {
  f8 r;
  r.lo = make_float4(bf2f((unsigned short)v[0]), bf2f((unsigned short)v[1]),
                     bf2f((unsigned short)v[2]), bf2f((unsigned short)v[3]));
  r.hi = make_float4(bf2f((unsigned short)v[4]), bf2f((unsigned short)v[5]),
                     bf2f((unsigned short)v[6]), bf2f((unsigned short)v[7]));
  return r;
}
__device__ __forceinline__ bf16x8 f2b8(const f8& v) {
  bf16x8 h;
  h[0] = (short)bf16rn(v.lo.x); h[1] = (short)bf16rn(v.lo.y);
  h[2] = (short)bf16rn(v.lo.z); h[3] = (short)bf16rn(v.lo.w);
  h[4] = (short)bf16rn(v.hi.x); h[5] = (short)bf16rn(v.hi.y);
  h[6] = (short)bf16rn(v.hi.z); h[7] = (short)bf16rn(v.hi.w);
  return h;
}
// relu(xv*ws + av*wn) over 8 cols; (0,0) -> 0
__device__ __forceinline__ f8 conv0f8(float xv, float av, const f8& ws, const f8& wn) {
  f8 t;
  t.lo.x = fmaxf(fmaf(xv, ws.lo.x, av * wn.lo.x), 0.f);
  t.lo.y = fmaxf(fmaf(xv, ws.lo.y, av * wn.lo.y), 0.f);
  t.lo.z = fmaxf(fmaf(xv, ws.lo.z, av * wn.lo.z), 0.f);
  t.lo.w = fmaxf(fmaf(xv, ws.lo.w, av * wn.lo.w), 0.f);
  t.hi.x = fmaxf(fmaf(xv, ws.hi.x, av * wn.hi.x), 0.f);
  t.hi.y = fmaxf(fmaf(xv, ws.hi.y, av * wn.hi.y), 0.f);
  t.hi.z = fmaxf(fmaf(xv, ws.hi.z, av * wn.hi.z), 0.f);
  t.hi.w = fmaxf(fmaf(xv, ws.hi.w, av * wn.hi.w), 0.f);
  return t;
}

// ---------- CSR build (dst-major neighbor lists) ----------

__global__ void hist_k(const int* __restrict__ ei, int* __restrict__ deg) {
  int e = blockIdx.x * blockDim.x + threadIdx.x;
  if (e < EE) atomicAdd(&deg[ei[EE + e]], 1);
}

__global__ __launch_bounds__(512) void scan1_k(const int* __restrict__ deg,
                                               int* __restrict__ rowstart,
                                               int* __restrict__ bsum) {
  __shared__ int s[512];
  int i = blockIdx.x * 512 + threadIdx.x;
  int v = (i < NN) ? deg[i] : 0;
  s[threadIdx.x] = v;
  __syncthreads();
  for (int off = 1; off < 512; off <<= 1) {
    int t = (threadIdx.x >= (unsigned)off) ? s[threadIdx.x - off] : 0;
    __syncthreads();
    s[threadIdx.x] += t;
    __syncthreads();
  }
  if (i < NN) rowstart[i] = s[threadIdx.x] - v;      // exclusive partial
  if (threadIdx.x == 511) bsum[blockIdx.x] = s[511];
}

__global__ void scan2_k(int* __restrict__ bsum) {
  if (threadIdx.x == 0) {
    int acc = 0;
    for (int k = 0; k < NBLK_SCAN; ++k) { int t = bsum[k]; bsum[k] = acc; acc += t; }
  }
}

__global__ __launch_bounds__(512) void scan3_k(int* __restrict__ rowstart,
                                               int* __restrict__ cursor,
                                               const int* __restrict__ bsum) {
  int i = blockIdx.x * 512 + threadIdx.x;
  if (i < NN) {
    int v = rowstart[i] + bsum[blockIdx.x];
    rowstart[i] = v;
    cursor[i] = v;
  }
  if (i == 0) rowstart[NN] = EE;
}

__global__ void fill_k(const int* __restrict__ ei, int* __restrict__ cursor,
                       int* __restrict__ nbr) {
  int e = blockIdx.x * blockDim.x + threadIdx.x;
  if (e >= EE) return;
  int d = ei[EE + e];
  int p = atomicAdd(&cursor[d], 1);
  nbr[p] = ei[e];
}

// ---------- weight prep: 9 matrices transposed+bf16 into wt[m][c][k]; also init mm ----------
// 0:Ws1 1:Wn1 2:Ws2 3:W1b 4:Wn2 5:W1c 6:W1a 7:W2 8:W3

__global__ void prepw_k(const float* __restrict__ Ws1, const float* __restrict__ Wn1,
                        const float* __restrict__ Ws2, const float* __restrict__ Wn2,
                        const float* __restrict__ W1,  const float* __restrict__ W2,
                        const float* __restrict__ W3,  unsigned short* __restrict__ wt,
                        unsigned* __restrict__ mm) {
  int idx = blockIdx.x * 256 + threadIdx.x;
  if (idx == 0) { mm[0] = 0xFFFFFFFFu; mm[1] = 0u; }
  if (idx >= 9 * 4096) return;
  int m = idx >> 12, r = idx & 4095;
  int c = r >> 6, k = r & 63;
  const float* src = Ws1;
  switch (m) {
    case 0: src = Ws1; break;
    case 1: src = Wn1; break;
    case 2: src = Ws2; break;
    case 3: src = W1 + 64 * 64; break;
    case 4: src = Wn2; break;
    case 5: src = W1 + 128 * 64; break;
    case 6: src = W1; break;
    case 7: src = W2; break;
    case 8: src = W3; break;
  }
  wt[idx] = bf16rn(src[k * 64 + c]);
}

// ---------- aggregation 0: agg0[n*4+m] = sum_{s in N(n)} x0[s*4+m] ----------

__global__ void agg0_gather_k(const float* __restrict__ x0,
                              const int* __restrict__ rowstart,
                              const int* __restrict__ nbr,
                              float* __restrict__ agg0) {
  int idx = blockIdx.x * blockDim.x + threadIdx.x;   // NROWS
  if (idx >= NROWS) return;
  int n = idx >> 2, m = idx & 3;
  int beg = rowstart[n], end = rowstart[n + 1];
  float acc = 0.0f;
  for (int i = beg; i < end; ++i) acc += x0[nbr[i] * 4 + m];
  agg0[idx] = acc;
}

// ---------- shared MFMA machinery (bf16 LDS tiles, 64-short rows + XOR slot swizzle) ----------

#define STAGE_WT(mi)                                                        \
  *(bf16x8*)&WTl[tid >> 3][(((tid & 7) ^ ((tid >> 3) & 7)) << 3)] =         \
      ((const bf16x8*)((const short*)wt + (mi) * 4096))[tid];

#define MFMA_PHASE(A0, A1)                                                   \
  _Pragma("unroll")                                                          \
  for (int kh = 0; kh < 2; ++kh) {                                           \
    int aslot = (kh << 2) | (lane >> 4);                                     \
    int scol  = ((aslot ^ (fl & 7)) << 3);                                   \
    bf16x8 af  = *(const bf16x8*)&XAs[mrow0 + fl][scol];                     \
    bf16x8 bf0 = *(const bf16x8*)&WTl[ncol0 + fl][scol];                     \
    bf16x8 bf1 = *(const bf16x8*)&WTl[ncol0 + 16 + fl][scol];                \
    A0 = __builtin_amdgcn_mfma_f32_16x16x32_bf16(af, bf0, A0, 0, 0, 0);      \
    A1 = __builtin_amdgcn_mfma_f32_16x16x32_bf16(af, bf1, A1, 0, 0, 0);      \
  }

#define DCOMMIT_RELU(A0, A1)                                            \
  _Pragma("unroll")                                                     \
  for (int j = 0; j < 4; ++j) {                                         \
    XAs[drow + j][swzc(drow + j, dc0)] = bf16rn(fmaxf(A0[j], 0.f));     \
    XAs[drow + j][swzc(drow + j, dc1)] = bf16rn(fmaxf(A1[j], 0.f));     \
  }

// XAs 16B write/read at (row r, col slice c8): swizzled slot
#define XSLOT(rr, cc8) ((((cc8) >> 3) ^ ((rr) & 7)) << 3)

// ---------- conv1 (gather fused, 512 thr, MFMA): x1 = relu(x0f@Ws1 + agg1@Wn1) -> bf16 ----------

__global__ __launch_bounds__(512, 4) void conv1_k(const float* __restrict__ x0,
                                                  const float* __restrict__ agg0,
                                                  const int* __restrict__ rowstart,
                                                  const int* __restrict__ nbr,
                                                  const float* __restrict__ Ws0,
                                                  const float* __restrict__ Wn0,
                                                  const unsigned short* __restrict__ wt,
                                                  unsigned short* __restrict__ x1b) {
  __shared__ unsigned short XAs[64][64];
  __shared__ unsigned short WTl[64][64];
  const int row0 = blockIdx.x << 6;
  const int nb0  = blockIdx.x << 4;
  const int tid = threadIdx.x;
  const int r   = tid >> 3;            // 0..63
  const int c8  = (tid & 7) << 3;      // 0..56
  const int lane  = tid & 63;
  const int wid   = tid >> 6;
  const int mrow0 = (wid >> 1) << 4;
  const int ncol0 = (wid & 1) << 5;
  const int fl    = lane & 15;
  const int drow  = mrow0 + ((lane >> 4) << 2);
  const int dc0   = ncol0 + fl, dc1 = ncol0 + 16 + fl;

  const int n = nb0 + (r >> 2), m = r & 3;
  const int beg = rowstart[n], end = rowstart[n + 1];

  f8 ws8, wn8;
  ws8.lo = *(const float4*)(Ws0 + c8); ws8.hi = *(const float4*)(Ws0 + c8 + 4);
  wn8.lo = *(const float4*)(Wn0 + c8); wn8.hi = *(const float4*)(Wn0 + c8 + 4);

  // stage XAs = x0feat (recomputed, bf16), WTl = Ws1^T
  *(bf16x8*)&XAs[r][XSLOT(r, c8)] =
      f2b8(conv0f8(x0[row0 + r], agg0[row0 + r], ws8, wn8));
  STAGE_WT(0);

  // gather agg1: 4-deep + 3-wide predicated tail
  f8 ga;
  {
    f8 a0 = zero8(), a1 = zero8();
    int i = beg;
    for (; i + 4 <= end; i += 4) {
      int s0 = nbr[i] * 4 + m, s1 = nbr[i+1] * 4 + m;
      int s2 = nbr[i+2] * 4 + m, s3 = nbr[i+3] * 4 + m;
      float xv0 = x0[s0], av0 = agg0[s0];
      float xv1 = x0[s1], av1 = agg0[s1];
      float xv2 = x0[s2], av2 = agg0[s2];
      float xv3 = x0[s3], av3 = agg0[s3];
      f8 t0 = conv0f8(xv0, av0, ws8, wn8); add8(a0, t0);
      f8 t1 = conv0f8(xv1, av1, ws8, wn8); add8(a1, t1);
      f8 t2 = conv0f8(xv2, av2, ws8, wn8); add8(a0, t2);
      f8 t3 = conv0f8(xv3, av3, ws8, wn8); add8(a1, t3);
    }
    bool p0 = i < end, p1 = i + 1 < end, p2 = i + 2 < end;
    float xv0 = 0.f, av0 = 0.f, xv1 = 0.f, av1 = 0.f, xv2 = 0.f, av2 = 0.f;
    if (p0) { int s = nbr[i]     * 4 + m; xv0 = x0[s]; av0 = agg0[s]; }
    if (p1) { int s = nbr[i + 1] * 4 + m; xv1 = x0[s]; av1 = agg0[s]; }
    if (p2) { int s = nbr[i + 2] * 4 + m; xv2 = x0[s]; av2 = agg0[s]; }
    if (p0) { f8 t = conv0f8(xv0, av0, ws8, wn8); add8(a0, t); }
    if (p1) { f8 t = conv0f8(xv1, av1, ws8, wn8); add8(a1, t); }
    if (p2) { f8 t = conv0f8(xv2, av2, ws8, wn8); add8(a0, t); }
    add8(a0, a1);
    ga = a0;
  }
  __syncthreads();

  // P1: x0f @ Ws1
  f32x4 a0v = {0.f,0.f,0.f,0.f}, a1v = {0.f,0.f,0.f,0.f};
  MFMA_PHASE(a0v, a1v);
  __syncthreads();
  *(bf16x8*)&XAs[r][XSLOT(r, c8)] = f2b8(ga);        // commit XAs = agg1
  STAGE_WT(1);                                       // WTl = Wn1^T
  __syncthreads();

  // P2: agg1 @ Wn1
  MFMA_PHASE(a0v, a1v);
  __syncthreads();
  DCOMMIT_RELU(a0v, a1v);                            // x1 (bf16) -> XAs
  __syncthreads();

  // coalesced copy XAs -> x1b (16B per thread)
  *(bf16x8*)(x1b + (size_t)(row0 + r) * 64 + c8) =
      *(const bf16x8*)&XAs[r][XSLOT(r, c8)];
}

// ---------- fused conv2 + 3-layer MLP + mean + min/max (512 thr, MFMA, bf16 LDS) ----------
//   P1 x1@Ws2->accP | P2 x1@W1b->accQ | P3 agg2@Wn2->accP, x2=relu
//   P4 x2@W1c->accQ | P5 x0f@W1a->accQ, h1=relu | P6 h1@W2 | P7 h2@W3

__global__ __launch_bounds__(512, 4) void fused2_k(const unsigned short* __restrict__ x1b,
    const int* __restrict__ rowstart, const int* __restrict__ nbr,
    const float* __restrict__ x0, const float* __restrict__ agg0,
    const float* __restrict__ Ws0, const float* __restrict__ Wn0,
    const unsigned short* __restrict__ wt,
    const float* __restrict__ b1, const float* __restrict__ b2,
    const float* __restrict__ b3,
    float* __restrict__ g, unsigned* __restrict__ mm) {
  __shared__ unsigned short XAs[64][64];
  __shared__ unsigned short WTl[64][64];
  __shared__ float red[16];
  const int row0 = blockIdx.x << 6;
  const int nb0  = blockIdx.x << 4;
  const int tid = threadIdx.x;
  const int r   = tid >> 3;            // 0..63
  const int c8  = (tid & 7) << 3;      // 0..56
  const int lane  = tid & 63;
  const int wid   = tid >> 6;
  const int mrow0 = (wid >> 1) << 4;
  const int ncol0 = (wid & 1) << 5;
  const int fl    = lane & 15;
  const int drow  = mrow0 + ((lane >> 4) << 2);
  const int dc0   = ncol0 + fl, dc1 = ncol0 + 16 + fl;

  const int n = nb0 + (r >> 2), m = r & 3;
  const int beg = rowstart[n], end = rowstart[n + 1];

  // ---- prologue: XAs <- x1 (bf16 direct, 16B), WTl <- Ws2^T ----
  *(bf16x8*)&XAs[r][XSLOT(r, c8)] =
      *(const bf16x8*)(x1b + (size_t)(row0 + r) * 64 + c8);
  STAGE_WT(2);

  // ---- gather agg2 from bf16 x1: 4-deep + 3-wide predicated tail ----
  f8 ga;
  {
    f8 a0 = zero8(), a1 = zero8();
    int i = beg;
    for (; i + 4 <= end; i += 4) {
      bf16x8 v0 = *(const bf16x8*)(x1b + (size_t)(nbr[i]   * 4 + m) * 64 + c8);
      bf16x8 v1 = *(const bf16x8*)(x1b + (size_t)(nbr[i+1] * 4 + m) * 64 + c8);
      bf16x8 v2 = *(const bf16x8*)(x1b + (size_t)(nbr[i+2] * 4 + m) * 64 + c8);
      bf16x8 v3 = *(const bf16x8*)(x1b + (size_t)(nbr[i+3] * 4 + m) * 64 + c8);
      f8 t0 = b2f8(v0); add8(a0, t0);
      f8 t1 = b2f8(v1); add8(a1, t1);
      f8 t2 = b2f8(v2); add8(a0, t2);
      f8 t3 = b2f8(v3); add8(a1, t3);
    }
    bool q0 = i < end, q1 = i + 1 < end, q2 = i + 2 < end;
    bf16x8 v0 = {}, v1 = {}, v2 = {};
    if (q0) v0 = *(const bf16x8*)(x1b + (size_t)(nbr[i]     * 4 + m) * 64 + c8);
    if (q1) v1 = *(const bf16x8*)(x1b + (size_t)(nbr[i + 1] * 4 + m) * 64 + c8);
    if (q2) v2 = *(const bf16x8*)(x1b + (size_t)(nbr[i + 2] * 4 + m) * 64 + c8);
    if (q0) { f8 t = b2f8(v0); add8(a0, t); }
    if (q1) { f8 t = b2f8(v1); add8(a1, t); }
    if (q2) { f8 t = b2f8(v2); add8(a0, t); }
    add8(a0, a1);
    ga = a0;
  }
  __syncthreads();

  // ---- P1: accP = x1 @ Ws2 ----
  f32x4 accP0 = {0.f,0.f,0.f,0.f}, accP1 = {0.f,0.f,0.f,0.f};
  MFMA_PHASE(accP0, accP1);
  __syncthreads();
  STAGE_WT(3);                                       // W1b^T
  __syncthreads();

  // ---- P2: accQ = b1 + x1 @ W1b ----
  f32x4 accQ0, accQ1;
  {
    float bv0 = b1[dc0], bv1 = b1[dc1];
    accQ0[0]=bv0; accQ0[1]=bv0; accQ0[2]=bv0; accQ0[3]=bv0;
    accQ1[0]=bv1; accQ1[1]=bv1; accQ1[2]=bv1; accQ1[3]=bv1;
  }
  MFMA_PHASE(accQ0, accQ1);
  __syncthreads();
  *(bf16x8*)&XAs[r][XSLOT(r, c8)] = f2b8(ga);        // commit XAs = agg2
  STAGE_WT(4);                                       // Wn2^T
  __syncthreads();

  // ---- P3: accP += agg2 @ Wn2 ; x2 = relu(accP) ----
  MFMA_PHASE(accP0, accP1);
  __syncthreads();
  DCOMMIT_RELU(accP0, accP1);                        // x2 -> XAs
  STAGE_WT(5);                                       // W1c^T
  __syncthreads();

  // ---- P4: accQ += x2 @ W1c ----
  MFMA_PHASE(accQ0, accQ1);
  __syncthreads();
  {
    f8 ws8, wn8;
    ws8.lo = *(const float4*)(Ws0 + c8); ws8.hi = *(const float4*)(Ws0 + c8 + 4);
    wn8.lo = *(const float4*)(Wn0 + c8); wn8.hi = *(const float4*)(Wn0 + c8 + 4);
    *(bf16x8*)&XAs[r][XSLOT(r, c8)] =
        f2b8(conv0f8(x0[row0 + r], agg0[row0 + r], ws8, wn8));  // XAs = x0feat
  }
  STAGE_WT(6);                                       // W1a^T
  __syncthreads();

  // ---- P5: accQ += x0f @ W1a ; h1 = relu(accQ) ----
  MFMA_PHASE(accQ0, accQ1);
  __syncthreads();
  DCOMMIT_RELU(accQ0, accQ1);                        // h1 -> XAs
  STAGE_WT(7);                                       // W2^T
  __syncthreads();

  // ---- P6: accR = b2 + h1 @ W2 ; h2 = relu ----
  f32x4 accR0, accR1;
  {
    float bv0 = b2[dc0], bv1 = b2[dc1];
    accR0[0]=bv0; accR0[1]=bv0; accR0[2]=bv0; accR0[3]=bv0;
    accR1[0]=bv1; accR1[1]=bv1; accR1[2]=bv1; accR1[3]=bv1;
  }
  MFMA_PHASE(accR0, accR1);
  __syncthreads();
  DCOMMIT_RELU(accR0, accR1);                        // h2 -> XAs
  STAGE_WT(8);                                       // W3^T
  __syncthreads();

  // ---- P7: accS = b3 + h2 @ W3 (no relu) ----
  f32x4 accS0, accS1;
  {
    float bv0 = b3[dc0], bv1 = b3[dc1];
    accS0[0]=bv0; accS0[1]=bv0; accS0[2]=bv0; accS0[3]=bv0;
    accS1[0]=bv1; accS1[1]=bv1; accS1[2]=bv1; accS1[3]=bv1;
  }
  MFMA_PHASE(accS0, accS1);
  __syncthreads();
#pragma unroll
  for (int j = 0; j < 4; ++j) {                      // h3 -> XAs (no relu)
    XAs[drow + j][swzc(drow + j, dc0)] = bf16rn(accS0[j]);
    XAs[drow + j][swzc(drow + j, dc1)] = bf16rn(accS1[j]);
  }
  __syncthreads();

  // ---- mean over M + per-block min/max ----
  float lmin = 3.4e38f, lmax = -3.4e38f;
  for (int k = tid; k < 1024; k += 512) {
    int nl = k >> 6, c = k & 63;
    float s = 0.25f * (bf2f(XAs[4*nl+0][swzc(4*nl+0, c)]) +
                       bf2f(XAs[4*nl+1][swzc(4*nl+1, c)]) +
                       bf2f(XAs[4*nl+2][swzc(4*nl+2, c)]) +
                       bf2f(XAs[4*nl+3][swzc(4*nl+3, c)]));
    g[(size_t)((row0 >> 2) + nl) * 64 + c] = s;
    lmin = fminf(lmin, s);
    lmax = fmaxf(lmax, s);
  }
#pragma unroll
  for (int off = 32; off; off >>= 1) {
    lmin = fminf(lmin, __shfl_xor(lmin, off));
    lmax = fmaxf(lmax, __shfl_xor(lmax, off));
  }
  if ((tid & 63) == 0) { red[tid >> 6] = lmin; red[8 + (tid >> 6)] = lmax; }
  __syncthreads();
  if (tid == 0) {
    float m0 = red[0], m1 = red[8];
#pragma unroll
    for (int w = 1; w < 8; ++w) {
      m0 = fminf(m0, red[w]);
      m1 = fmaxf(m1, red[8 + w]);
    }
    atomicMin(&mm[0], enc_f(m0));
    atomicMax(&mm[1], enc_f(m1));
  }
}

// ---------- fused rescale + pool + output linear: one block per batch b ----------
// out[b] = sc * sum_{n in seg(b)} sum_c (g[n,c]-gmin) * Wo[c] + bo
// seg(b) found by binary search in sorted batch[].

__global__ __launch_bounds__(256) void poolout_k(const float* __restrict__ g,
                                                 const int* __restrict__ batch,
                                                 const unsigned* __restrict__ mm,
                                                 const float* __restrict__ Wo,
                                                 const float* __restrict__ bo,
                                                 float* __restrict__ out) {
  __shared__ int seg[2];
  __shared__ float red[4];
  const int b = blockIdx.x;
  const int tid = threadIdx.x;
  if (tid < 2) {
    int target = b + tid;
    int lo = 0, hi = NN;
    while (lo < hi) {
      int mid = (lo + hi) >> 1;
      if (batch[mid] < target) lo = mid + 1; else hi = mid;
    }
    seg[tid] = lo;
  }
  __syncthreads();
  const int lo = seg[0], hi = seg[1];
  const float gmin = dec_f(mm[0]);
  const float sc = 2.0f / (dec_f(mm[1]) - gmin);
  const int c = tid & 63;
  const float wv = Wo[c];
  float acc = 0.f;
  for (int nn = lo + (tid >> 6); nn < hi; nn += 4)
    acc += (g[(size_t)nn * 64 + c] - gmin) * wv;
#pragma unroll
  for (int off = 32; off; off >>= 1) acc += __shfl_xor(acc, off);
  if ((tid & 63) == 0) red[tid >> 6] = acc;
  __syncthreads();
  if (tid == 0)
    out[b] = sc * (red[0] + red[1] + red[2] + red[3]) + bo[0];
}

// ---------- launch ----------

extern "C" void kernel_launch(void* const* d_in, const int* in_sizes, int n_in,
                              void* d_out, int out_size, void* d_ws, size_t ws_size,
                              hipStream_t stream) {
  const float* x0   = (const float*)d_in[0];
  const int*   ei   = (const int*)d_in[1];
  const int*   batch= (const int*)d_in[2];
  const float* Ws0  = (const float*)d_in[3];
  const float* Wn0  = (const float*)d_in[4];
  const float* Ws1  = (const float*)d_in[5];
  const float* Wn1  = (const float*)d_in[6];
  const float* Ws2  = (const float*)d_in[7];
  const float* Wn2  = (const float*)d_in[8];
  const float* W1   = (const float*)d_in[9];
  const float* b1   = (const float*)d_in[10];
  const float* W2   = (const float*)d_in[11];
  const float* b2   = (const float*)d_in[12];
  const float* W3   = (const float*)d_in[13];
  const float* b3   = (const float*)d_in[14];
  const float* Wo   = (const float*)d_in[15];
  const float* bo   = (const float*)d_in[16];
  float* out = (float*)d_out;

  unsigned short* x1b = (unsigned short*)d_ws;        // [NROWS,64] bf16
  unsigned short* wt  = x1b + (size_t)NROWS * 64;     // [9][64][64] bf16 transposed
  float* agg0   = (float*)(wt + 9 * 4096);            // [NROWS]
  float* g      = agg0 + NROWS;                       // [NN,64]
  unsigned* mm  = (unsigned*)(g + (size_t)NN * 64);   // [2]
  int* deg      = (int*)(mm + 2);                     // [NN]
  int* rowstart = deg + NN;                           // [NN+1]
  int* cursor   = rowstart + NN + 1;                  // [NN]
  int* nbr      = cursor + NN;                        // [EE]
  int* bsum     = nbr + EE;                           // [NBLK_SCAN]

  // ---- CSR build + weight prep (prepw also inits mm) ----
  hipMemsetAsync(deg, 0, NN * sizeof(int), stream);
  hist_k<<<(EE + 255) / 256, 256, 0, stream>>>(ei, deg);
  prepw_k<<<144, 256, 0, stream>>>(Ws1, Wn1, Ws2, Wn2, W1, W2, W3, wt, mm);
  scan1_k<<<NBLK_SCAN, 512, 0, stream>>>(deg, rowstart, bsum);
  scan2_k<<<1, 64, 0, stream>>>(bsum);
  scan3_k<<<NBLK_SCAN, 512, 0, stream>>>(rowstart, cursor, bsum);
  fill_k<<<(EE + 255) / 256, 256, 0, stream>>>(ei, cursor, nbr);

  // ---- layer 0 aggregate (scalar) ----
  agg0_gather_k<<<(NROWS + 255) / 256, 256, 0, stream>>>(x0, rowstart, nbr, agg0);

  // ---- layer 1 (agg1 gather fused, MFMA) -> x1 (bf16) ----
  conv1_k<<<NROWS / 64, 512, 0, stream>>>(x0, agg0, rowstart, nbr,
                                          Ws0, Wn0, wt, x1b);

  // ---- fused conv2 + MLP + mean + min/max (MFMA, bf16 LDS, swizzled) ----
  fused2_k<<<NROWS / 64, 512, 0, stream>>>(x1b, rowstart, nbr, x0, agg0,
                                           Ws0, Wn0, wt, b1, b2, b3, g, mm);

  // ---- fused rescale + pool + output linear ----
  poolout_k<<<BB, 256, 0, stream>>>(g, batch, mm, Wo, bo, out);
}

// Round 19
// 210.316 us; speedup vs baseline: 1.1728x; 1.1728x over previous
//
#include <hip/hip_runtime.h>
#include <math.h>

#define NN 50000
#define MM 4
#define EE 400000
#define BB 64
#define NROWS (NN*MM)           // 200000
#define NBLK_SCAN 98            // ceil(50000/512)

typedef __attribute__((ext_vector_type(8))) short bf16x8;
typedef __attribute__((ext_vector_type(4))) float f32x4;

struct f8 { float4 lo, hi; };

// ---------- helpers ----------

__device__ __forceinline__ unsigned enc_f(float f) {
  unsigned u = __float_as_uint(f);
  return (u & 0x80000000u) ? ~u : (u | 0x80000000u);
}
__device__ __forceinline__ float dec_f(unsigned u) {
  return (u & 0x80000000u) ? __uint_as_float(u ^ 0x80000000u) : __uint_as_float(~u);
}

__device__ __forceinline__ unsigned short bf16rn(float f) {
  unsigned u = __float_as_uint(f);
  return (unsigned short)((u + 0x7FFFu + ((u >> 16) & 1u)) >> 16);
}
__device__ __forceinline__ float bf2f(unsigned short h) {
  return __uint_as_float(((unsigned)h) << 16);
}

// swizzled scalar column within a 64-short row: 16B slot ^= (row & 7)
__device__ __forceinline__ int swzc(int row, int col) {
  return ((((col >> 3) ^ (row & 7)) << 3)) | (col & 7);
}

__device__ __forceinline__ f8 zero8() {
  f8 r; r.lo = make_float4(0.f,0.f,0.f,0.f); r.hi = r.lo; return r;
}
__device__ __forceinline__ void add8(f8& a, const f8& b) {
  a.lo.x += b.lo.x; a.lo.y += b.lo.y; a.lo.z += b.lo.z; a.lo.w += b.lo.w;
  a.hi.x += b.hi.x; a.hi.y += b.hi.y; a.hi.z += b.hi.z; a.hi.w += b.hi.w;
}
__device__ __forceinline__ f8 b2f8(bf16x8 v) {
  f8 r;
  r.lo = make_float4(bf2f((unsigned short)v[0]), bf2f((unsigned short)v[1]),
                     bf2f((unsigned short)v[2]), bf2f((unsigned short)v[3]));
  r.hi = make_float4(bf2f((unsigned short)v[4]), bf2f((unsigned short)v[5]),
                     bf2f((unsigned short)v[6]), bf2f((unsigned short)v[7]));
  return r;
}
__device__ __forceinline__ bf16x8 f2b8(const f8& v) {
  bf16x8 h;
  h[0] = (short)bf16rn(v.lo.x); h[1] = (short)bf16rn(v.lo.y);
  h[2] = (short)bf16rn(v.lo.z); h[3] = (short)bf16rn(v.lo.w);
  h[4] = (short)bf16rn(v.hi.x); h[5] = (short)bf16rn(v.hi.y);
  h[6] = (short)bf16rn(v.hi.z); h[7] = (short)bf16rn(v.hi.w);
  return h;
}
// relu(xv*ws + av*wn) over 8 cols; (0,0) -> 0
__device__ __forceinline__ f8 conv0f8(float xv, float av, const f8& ws, const f8& wn) {
  f8 t;
  t.lo.x = fmaxf(fmaf(xv, ws.lo.x, av * wn.lo.x), 0.f);
  t.lo.y = fmaxf(fmaf(xv, ws.lo.y, av * wn.lo.y), 0.f);
  t.lo.z = fmaxf(fmaf(xv, ws.lo.z, av * wn.lo.z), 0.f);
  t.lo.w = fmaxf(fmaf(xv, ws.lo.w, av * wn.lo.w), 0.f);
  t.hi.x = fmaxf(fmaf(xv, ws.hi.x, av * wn.hi.x), 0.f);
  t.hi.y = fmaxf(fmaf(xv, ws.hi.y, av * wn.hi.y), 0.f);
  t.hi.z = fmaxf(fmaf(xv, ws.hi.z, av * wn.hi.z), 0.f);
  t.hi.w = fmaxf(fmaf(xv, ws.hi.w, av * wn.hi.w), 0.f);
  return t;
}

// ---------- CSR build (dst-major neighbor lists) ----------

__global__ void hist_k(const int* __restrict__ ei, int* __restrict__ deg) {
  int e = blockIdx.x * blockDim.x + threadIdx.x;
  if (e < EE) atomicAdd(&deg[ei[EE + e]], 1);
}

__global__ __launch_bounds__(512) void scan1_k(const int* __restrict__ deg,
                                               int* __restrict__ rowstart,
                                               int* __restrict__ bsum) {
  __shared__ int s[512];
  int i = blockIdx.x * 512 + threadIdx.x;
  int v = (i < NN) ? deg[i] : 0;
  s[threadIdx.x] = v;
  __syncthreads();
  for (int off = 1; off < 512; off <<= 1) {
    int t = (threadIdx.x >= (unsigned)off) ? s[threadIdx.x - off] : 0;
    __syncthreads();
    s[threadIdx.x] += t;
    __syncthreads();
  }
  if (i < NN) rowstart[i] = s[threadIdx.x] - v;      // exclusive partial
  if (threadIdx.x == 511) bsum[blockIdx.x] = s[511];
}

__global__ void scan2_k(int* __restrict__ bsum) {
  if (threadIdx.x == 0) {
    int acc = 0;
    for (int k = 0; k < NBLK_SCAN; ++k) { int t = bsum[k]; bsum[k] = acc; acc += t; }
  }
}

__global__ __launch_bounds__(512) void scan3_k(int* __restrict__ rowstart,
                                               int* __restrict__ cursor,
                                               const int* __restrict__ bsum) {
  int i = blockIdx.x * 512 + threadIdx.x;
  if (i < NN) {
    int v = rowstart[i] + bsum[blockIdx.x];
    rowstart[i] = v;
    cursor[i] = v;
  }
  if (i == 0) rowstart[NN] = EE;
}

__global__ void fill_k(const int* __restrict__ ei, int* __restrict__ cursor,
                       int* __restrict__ nbr) {
  int e = blockIdx.x * blockDim.x + threadIdx.x;
  if (e >= EE) return;
  int d = ei[EE + e];
  int p = atomicAdd(&cursor[d], 1);
  nbr[p] = ei[e];
}

// ---------- weight prep: 9 matrices transposed+bf16 into wt[m][c][k] ----------
// 0:Ws1 1:Wn1 2:Ws2 3:W1b 4:Wn2 5:W1c 6:W1a 7:W2 8:W3

__global__ void prepw_k(const float* __restrict__ Ws1, const float* __restrict__ Wn1,
                        const float* __restrict__ Ws2, const float* __restrict__ Wn2,
                        const float* __restrict__ W1,  const float* __restrict__ W2,
                        const float* __restrict__ W3,  unsigned short* __restrict__ wt) {
  int idx = blockIdx.x * 256 + threadIdx.x;
  if (idx >= 9 * 4096) return;
  int m = idx >> 12, r = idx & 4095;
  int c = r >> 6, k = r & 63;
  const float* src = Ws1;
  switch (m) {
    case 0: src = Ws1; break;
    case 1: src = Wn1; break;
    case 2: src = Ws2; break;
    case 3: src = W1 + 64 * 64; break;
    case 4: src = Wn2; break;
    case 5: src = W1 + 128 * 64; break;
    case 6: src = W1; break;
    case 7: src = W2; break;
    case 8: src = W3; break;
  }
  wt[idx] = bf16rn(src[k * 64 + c]);
}

// ---------- aggregation 0: agg0[n*4+m] = sum_{s in N(n)} x0[s*4+m] ----------

__global__ void agg0_gather_k(const float* __restrict__ x0,
                              const int* __restrict__ rowstart,
                              const int* __restrict__ nbr,
                              float* __restrict__ agg0) {
  int idx = blockIdx.x * blockDim.x + threadIdx.x;   // NROWS
  if (idx >= NROWS) return;
  int n = idx >> 2, m = idx & 3;
  int beg = rowstart[n], end = rowstart[n + 1];
  float acc = 0.0f;
  for (int i = beg; i < end; ++i) acc += x0[nbr[i] * 4 + m];
  agg0[idx] = acc;
}

// ---------- shared MFMA machinery (bf16 LDS tiles, 64-short rows + XOR slot swizzle) ----------

#define STAGE_WT(mi)                                                        \
  *(bf16x8*)&WTl[tid >> 3][(((tid & 7) ^ ((tid >> 3) & 7)) << 3)] =         \
      ((const bf16x8*)((const short*)wt + (mi) * 4096))[tid];

#define MFMA_PHASE(A0, A1)                                                   \
  _Pragma("unroll")                                                          \
  for (int kh = 0; kh < 2; ++kh) {                                           \
    int aslot = (kh << 2) | (lane >> 4);                                     \
    int scol  = ((aslot ^ (fl & 7)) << 3);                                   \
    bf16x8 af  = *(const bf16x8*)&XAs[mrow0 + fl][scol];                     \
    bf16x8 bf0 = *(const bf16x8*)&WTl[ncol0 + fl][scol];                     \
    bf16x8 bf1 = *(const bf16x8*)&WTl[ncol0 + 16 + fl][scol];                \
    A0 = __builtin_amdgcn_mfma_f32_16x16x32_bf16(af, bf0, A0, 0, 0, 0);      \
    A1 = __builtin_amdgcn_mfma_f32_16x16x32_bf16(af, bf1, A1, 0, 0, 0);      \
  }

#define DCOMMIT_RELU(A0, A1)                                            \
  _Pragma("unroll")                                                     \
  for (int j = 0; j < 4; ++j) {                                         \
    XAs[drow + j][swzc(drow + j, dc0)] = bf16rn(fmaxf(A0[j], 0.f));     \
    XAs[drow + j][swzc(drow + j, dc1)] = bf16rn(fmaxf(A1[j], 0.f));     \
  }

// XAs 16B write/read at (row r, col slice c8): swizzled slot
#define XSLOT(rr, cc8) ((((cc8) >> 3) ^ ((rr) & 7)) << 3)

// ---------- conv1 (gather fused, 512 thr, MFMA): x1 = relu(x0f@Ws1 + agg1@Wn1) -> bf16 ----------

__global__ __launch_bounds__(512, 4) void conv1_k(const float* __restrict__ x0,
                                                  const float* __restrict__ agg0,
                                                  const int* __restrict__ rowstart,
                                                  const int* __restrict__ nbr,
                                                  const float* __restrict__ Ws0,
                                                  const float* __restrict__ Wn0,
                                                  const unsigned short* __restrict__ wt,
                                                  unsigned short* __restrict__ x1b) {
  __shared__ unsigned short XAs[64][64];
  __shared__ unsigned short WTl[64][64];
  const int row0 = blockIdx.x << 6;
  const int nb0  = blockIdx.x << 4;
  const int tid = threadIdx.x;
  const int r   = tid >> 3;            // 0..63
  const int c8  = (tid & 7) << 3;      // 0..56
  const int lane  = tid & 63;
  const int wid   = tid >> 6;
  const int mrow0 = (wid >> 1) << 4;
  const int ncol0 = (wid & 1) << 5;
  const int fl    = lane & 15;
  const int drow  = mrow0 + ((lane >> 4) << 2);
  const int dc0   = ncol0 + fl, dc1 = ncol0 + 16 + fl;

  const int n = nb0 + (r >> 2), m = r & 3;
  const int beg = rowstart[n], end = rowstart[n + 1];

  f8 ws8, wn8;
  ws8.lo = *(const float4*)(Ws0 + c8); ws8.hi = *(const float4*)(Ws0 + c8 + 4);
  wn8.lo = *(const float4*)(Wn0 + c8); wn8.hi = *(const float4*)(Wn0 + c8 + 4);

  // stage XAs = x0feat (recomputed, bf16), WTl = Ws1^T
  *(bf16x8*)&XAs[r][XSLOT(r, c8)] =
      f2b8(conv0f8(x0[row0 + r], agg0[row0 + r], ws8, wn8));
  STAGE_WT(0);

  // gather agg1: 4-deep + 3-wide predicated tail
  f8 ga;
  {
    f8 a0 = zero8(), a1 = zero8();
    int i = beg;
    for (; i + 4 <= end; i += 4) {
      int s0 = nbr[i] * 4 + m, s1 = nbr[i+1] * 4 + m;
      int s2 = nbr[i+2] * 4 + m, s3 = nbr[i+3] * 4 + m;
      float xv0 = x0[s0], av0 = agg0[s0];
      float xv1 = x0[s1], av1 = agg0[s1];
      float xv2 = x0[s2], av2 = agg0[s2];
      float xv3 = x0[s3], av3 = agg0[s3];
      f8 t0 = conv0f8(xv0, av0, ws8, wn8); add8(a0, t0);
      f8 t1 = conv0f8(xv1, av1, ws8, wn8); add8(a1, t1);
      f8 t2 = conv0f8(xv2, av2, ws8, wn8); add8(a0, t2);
      f8 t3 = conv0f8(xv3, av3, ws8, wn8); add8(a1, t3);
    }
    bool p0 = i < end, p1 = i + 1 < end, p2 = i + 2 < end;
    float xv0 = 0.f, av0 = 0.f, xv1 = 0.f, av1 = 0.f, xv2 = 0.f, av2 = 0.f;
    if (p0) { int s = nbr[i]     * 4 + m; xv0 = x0[s]; av0 = agg0[s]; }
    if (p1) { int s = nbr[i + 1] * 4 + m; xv1 = x0[s]; av1 = agg0[s]; }
    if (p2) { int s = nbr[i + 2] * 4 + m; xv2 = x0[s]; av2 = agg0[s]; }
    if (p0) { f8 t = conv0f8(xv0, av0, ws8, wn8); add8(a0, t); }
    if (p1) { f8 t = conv0f8(xv1, av1, ws8, wn8); add8(a1, t); }
    if (p2) { f8 t = conv0f8(xv2, av2, ws8, wn8); add8(a0, t); }
    add8(a0, a1);
    ga = a0;
  }
  __syncthreads();

  // P1: x0f @ Ws1
  f32x4 a0v = {0.f,0.f,0.f,0.f}, a1v = {0.f,0.f,0.f,0.f};
  MFMA_PHASE(a0v, a1v);
  __syncthreads();
  *(bf16x8*)&XAs[r][XSLOT(r, c8)] = f2b8(ga);        // commit XAs = agg1
  STAGE_WT(1);                                       // WTl = Wn1^T
  __syncthreads();

  // P2: agg1 @ Wn1
  MFMA_PHASE(a0v, a1v);
  __syncthreads();
  DCOMMIT_RELU(a0v, a1v);                            // x1 (bf16) -> XAs
  __syncthreads();

  // coalesced copy XAs -> x1b (16B per thread)
  *(bf16x8*)(x1b + (size_t)(row0 + r) * 64 + c8) =
      *(const bf16x8*)&XAs[r][XSLOT(r, c8)];
}

// ---------- fused conv2 + 3-layer MLP + mean + min/max (512 thr, MFMA, bf16 LDS) ----------
//   P1 x1@Ws2->accP | P2 x1@W1b->accQ | P3 agg2@Wn2->accP, x2=relu
//   P4 x2@W1c->accQ | P5 x0f@W1a->accQ, h1=relu | P6 h1@W2 | P7 h2@W3

__global__ __launch_bounds__(512, 4) void fused2_k(const unsigned short* __restrict__ x1b,
    const int* __restrict__ rowstart, const int* __restrict__ nbr,
    const float* __restrict__ x0, const float* __restrict__ agg0,
    const float* __restrict__ Ws0, const float* __restrict__ Wn0,
    const unsigned short* __restrict__ wt,
    const float* __restrict__ b1, const float* __restrict__ b2,
    const float* __restrict__ b3,
    float* __restrict__ g, unsigned* __restrict__ mm) {
  __shared__ unsigned short XAs[64][64];
  __shared__ unsigned short WTl[64][64];
  __shared__ float red[16];
  const int row0 = blockIdx.x << 6;
  const int nb0  = blockIdx.x << 4;
  const int tid = threadIdx.x;
  const int r   = tid >> 3;            // 0..63
  const int c8  = (tid & 7) << 3;      // 0..56
  const int lane  = tid & 63;
  const int wid   = tid >> 6;
  const int mrow0 = (wid >> 1) << 4;
  const int ncol0 = (wid & 1) << 5;
  const int fl    = lane & 15;
  const int drow  = mrow0 + ((lane >> 4) << 2);
  const int dc0   = ncol0 + fl, dc1 = ncol0 + 16 + fl;

  const int n = nb0 + (r >> 2), m = r & 3;
  const int beg = rowstart[n], end = rowstart[n + 1];

  // ---- prologue: XAs <- x1 (bf16 direct, 16B), WTl <- Ws2^T ----
  *(bf16x8*)&XAs[r][XSLOT(r, c8)] =
      *(const bf16x8*)(x1b + (size_t)(row0 + r) * 64 + c8);
  STAGE_WT(2);

  // ---- gather agg2 from bf16 x1: 4-deep + 3-wide predicated tail ----
  f8 ga;
  {
    f8 a0 = zero8(), a1 = zero8();
    int i = beg;
    for (; i + 4 <= end; i += 4) {
      bf16x8 v0 = *(const bf16x8*)(x1b + (size_t)(nbr[i]   * 4 + m) * 64 + c8);
      bf16x8 v1 = *(const bf16x8*)(x1b + (size_t)(nbr[i+1] * 4 + m) * 64 + c8);
      bf16x8 v2 = *(const bf16x8*)(x1b + (size_t)(nbr[i+2] * 4 + m) * 64 + c8);
      bf16x8 v3 = *(const bf16x8*)(x1b + (size_t)(nbr[i+3] * 4 + m) * 64 + c8);
      f8 t0 = b2f8(v0); add8(a0, t0);
      f8 t1 = b2f8(v1); add8(a1, t1);
      f8 t2 = b2f8(v2); add8(a0, t2);
      f8 t3 = b2f8(v3); add8(a1, t3);
    }
    bool q0 = i < end, q1 = i + 1 < end, q2 = i + 2 < end;
    bf16x8 v0 = {}, v1 = {}, v2 = {};
    if (q0) v0 = *(const bf16x8*)(x1b + (size_t)(nbr[i]     * 4 + m) * 64 + c8);
    if (q1) v1 = *(const bf16x8*)(x1b + (size_t)(nbr[i + 1] * 4 + m) * 64 + c8);
    if (q2) v2 = *(const bf16x8*)(x1b + (size_t)(nbr[i + 2] * 4 + m) * 64 + c8);
    if (q0) { f8 t = b2f8(v0); add8(a0, t); }
    if (q1) { f8 t = b2f8(v1); add8(a1, t); }
    if (q2) { f8 t = b2f8(v2); add8(a0, t); }
    add8(a0, a1);
    ga = a0;
  }
  __syncthreads();

  // ---- P1: accP = x1 @ Ws2 ----
  f32x4 accP0 = {0.f,0.f,0.f,0.f}, accP1 = {0.f,0.f,0.f,0.f};
  MFMA_PHASE(accP0, accP1);
  __syncthreads();
  STAGE_WT(3);                                       // W1b^T
  __syncthreads();

  // ---- P2: accQ = b1 + x1 @ W1b ----
  f32x4 accQ0, accQ1;
  {
    float bv0 = b1[dc0], bv1 = b1[dc1];
    accQ0[0]=bv0; accQ0[1]=bv0; accQ0[2]=bv0; accQ0[3]=bv0;
    accQ1[0]=bv1; accQ1[1]=bv1; accQ1[2]=bv1; accQ1[3]=bv1;
  }
  MFMA_PHASE(accQ0, accQ1);
  __syncthreads();
  *(bf16x8*)&XAs[r][XSLOT(r, c8)] = f2b8(ga);        // commit XAs = agg2
  STAGE_WT(4);                                       // Wn2^T
  __syncthreads();

  // ---- P3: accP += agg2 @ Wn2 ; x2 = relu(accP) ----
  MFMA_PHASE(accP0, accP1);
  __syncthreads();
  DCOMMIT_RELU(accP0, accP1);                        // x2 -> XAs
  STAGE_WT(5);                                       // W1c^T
  __syncthreads();

  // ---- P4: accQ += x2 @ W1c ----
  MFMA_PHASE(accQ0, accQ1);
  __syncthreads();
  {
    f8 ws8, wn8;
    ws8.lo = *(const float4*)(Ws0 + c8); ws8.hi = *(const float4*)(Ws0 + c8 + 4);
    wn8.lo = *(const float4*)(Wn0 + c8); wn8.hi = *(const float4*)(Wn0 + c8 + 4);
    *(bf16x8*)&XAs[r][XSLOT(r, c8)] =
        f2b8(conv0f8(x0[row0 + r], agg0[row0 + r], ws8, wn8));  // XAs = x0feat
  }
  STAGE_WT(6);                                       // W1a^T
  __syncthreads();

  // ---- P5: accQ += x0f @ W1a ; h1 = relu(accQ) ----
  MFMA_PHASE(accQ0, accQ1);
  __syncthreads();
  DCOMMIT_RELU(accQ0, accQ1);                        // h1 -> XAs
  STAGE_WT(7);                                       // W2^T
  __syncthreads();

  // ---- P6: accR = b2 + h1 @ W2 ; h2 = relu ----
  f32x4 accR0, accR1;
  {
    float bv0 = b2[dc0], bv1 = b2[dc1];
    accR0[0]=bv0; accR0[1]=bv0; accR0[2]=bv0; accR0[3]=bv0;
    accR1[0]=bv1; accR1[1]=bv1; accR1[2]=bv1; accR1[3]=bv1;
  }
  MFMA_PHASE(accR0, accR1);
  __syncthreads();
  DCOMMIT_RELU(accR0, accR1);                        // h2 -> XAs
  STAGE_WT(8);                                       // W3^T
  __syncthreads();

  // ---- P7: accS = b3 + h2 @ W3 (no relu) ----
  f32x4 accS0, accS1;
  {
    float bv0 = b3[dc0], bv1 = b3[dc1];
    accS0[0]=bv0; accS0[1]=bv0; accS0[2]=bv0; accS0[3]=bv0;
    accS1[0]=bv1; accS1[1]=bv1; accS1[2]=bv1; accS1[3]=bv1;
  }
  MFMA_PHASE(accS0, accS1);
  __syncthreads();
#pragma unroll
  for (int j = 0; j < 4; ++j) {                      // h3 -> XAs (no relu)
    XAs[drow + j][swzc(drow + j, dc0)] = bf16rn(accS0[j]);
    XAs[drow + j][swzc(drow + j, dc1)] = bf16rn(accS1[j]);
  }
  __syncthreads();

  // ---- mean over M + per-block min/max ----
  float lmin = 3.4e38f, lmax = -3.4e38f;
  for (int k = tid; k < 1024; k += 512) {
    int nl = k >> 6, c = k & 63;
    float s = 0.25f * (bf2f(XAs[4*nl+0][swzc(4*nl+0, c)]) +
                       bf2f(XAs[4*nl+1][swzc(4*nl+1, c)]) +
                       bf2f(XAs[4*nl+2][swzc(4*nl+2, c)]) +
                       bf2f(XAs[4*nl+3][swzc(4*nl+3, c)]));
    g[(size_t)((row0 >> 2) + nl) * 64 + c] = s;
    lmin = fminf(lmin, s);
    lmax = fmaxf(lmax, s);
  }
#pragma unroll
  for (int off = 32; off; off >>= 1) {
    lmin = fminf(lmin, __shfl_xor(lmin, off));
    lmax = fmaxf(lmax, __shfl_xor(lmax, off));
  }
  if ((tid & 63) == 0) { red[tid >> 6] = lmin; red[8 + (tid >> 6)] = lmax; }
  __syncthreads();
  if (tid == 0) {
    float m0 = red[0], m1 = red[8];
#pragma unroll
    for (int w = 1; w < 8; ++w) {
      m0 = fminf(m0, red[w]);
      m1 = fmaxf(m1, red[8 + w]);
    }
    atomicMin(&mm[0], enc_f(m0));
    atomicMax(&mm[1], enc_f(m1));
  }
}

// ---------- rescale + pool (sorted batch -> run-length accumulate) ----------

__global__ __launch_bounds__(256) void pool2_k(const float* __restrict__ g,
                                               const int* __restrict__ batch,
                                               const unsigned* __restrict__ mm,
                                               float* __restrict__ pooled) {
  int c = threadIdx.x & 63;
  int grp = threadIdx.x >> 6;                        // 0..3
  int base = blockIdx.x * 64 + grp * 16;             // 16 consecutive nodes per group
  float gmin = dec_f(mm[0]);
  float sc = 2.0f / (dec_f(mm[1]) - gmin);
  float acc = 0.0f; int cur = -1;
  for (int i = 0; i < 16; ++i) {
    int n = base + i;
    if (n >= NN) break;
    int b = batch[n];
    if (b != cur) {
      if (cur >= 0) unsafeAtomicAdd(&pooled[(cur << 6) + c], acc);
      cur = b; acc = 0.0f;
    }
    acc += (g[(size_t)n * 64 + c] - gmin) * sc;
  }
  if (cur >= 0) unsafeAtomicAdd(&pooled[(cur << 6) + c], acc);
}

// ---------- out[b] = pooled[b,:] . Wo + bo ----------

__global__ void out_k(const float* __restrict__ pooled, const float* __restrict__ Wo,
                      const float* __restrict__ bo, float* __restrict__ out) {
  int b = blockIdx.x, l = threadIdx.x;
  float v = pooled[(b << 6) + l] * Wo[l];
#pragma unroll
  for (int off = 32; off; off >>= 1) v += __shfl_xor(v, off);
  if (l == 0) out[b] = v + bo[0];
}

// ---------- launch ----------

extern "C" void kernel_launch(void* const* d_in, const int* in_sizes, int n_in,
                              void* d_out, int out_size, void* d_ws, size_t ws_size,
                              hipStream_t stream) {
  const float* x0   = (const float*)d_in[0];
  const int*   ei   = (const int*)d_in[1];
  const int*   batch= (const int*)d_in[2];
  const float* Ws0  = (const float*)d_in[3];
  const float* Wn0  = (const float*)d_in[4];
  const float* Ws1  = (const float*)d_in[5];
  const float* Wn1  = (const float*)d_in[6];
  const float* Ws2  = (const float*)d_in[7];
  const float* Wn2  = (const float*)d_in[8];
  const float* W1   = (const float*)d_in[9];
  const float* b1   = (const float*)d_in[10];
  const float* W2   = (const float*)d_in[11];
  const float* b2   = (const float*)d_in[12];
  const float* W3   = (const float*)d_in[13];
  const float* b3   = (const float*)d_in[14];
  const float* Wo   = (const float*)d_in[15];
  const float* bo   = (const float*)d_in[16];
  float* out = (float*)d_out;

  unsigned short* x1b = (unsigned short*)d_ws;        // [NROWS,64] bf16
  unsigned short* wt  = x1b + (size_t)NROWS * 64;     // [9][64][64] bf16 transposed
  float* agg0   = (float*)(wt + 9 * 4096);            // [NROWS]
  float* g      = agg0 + NROWS;                       // [NN,64]
  float* pooled = g    + (size_t)NN * 64;             // [BB,64]
  unsigned* mm  = (unsigned*)(pooled + BB * 64);      // [2]
  int* deg      = (int*)(mm + 2);                     // [NN]
  int* rowstart = deg + NN;                           // [NN+1]
  int* cursor   = rowstart + NN + 1;                  // [NN]
  int* nbr      = cursor + NN;                        // [EE]
  int* bsum     = nbr + EE;                           // [NBLK_SCAN]

  // ---- CSR build + weight prep ----
  hipMemsetAsync(deg, 0, NN * sizeof(int), stream);
  hist_k<<<(EE + 255) / 256, 256, 0, stream>>>(ei, deg);
  prepw_k<<<144, 256, 0, stream>>>(Ws1, Wn1, Ws2, Wn2, W1, W2, W3, wt);
  scan1_k<<<NBLK_SCAN, 512, 0, stream>>>(deg, rowstart, bsum);
  scan2_k<<<1, 64, 0, stream>>>(bsum);
  scan3_k<<<NBLK_SCAN, 512, 0, stream>>>(rowstart, cursor, bsum);
  fill_k<<<(EE + 255) / 256, 256, 0, stream>>>(ei, cursor, nbr);

  // ---- layer 0 aggregate (scalar) ----
  agg0_gather_k<<<(NROWS + 255) / 256, 256, 0, stream>>>(x0, rowstart, nbr, agg0);

  // ---- layer 1 (agg1 gather fused, MFMA) -> x1 (bf16) ----
  conv1_k<<<NROWS / 64, 512, 0, stream>>>(x0, agg0, rowstart, nbr,
                                          Ws0, Wn0, wt, x1b);

  // ---- fused conv2 + MLP + mean + min/max (MFMA, bf16 LDS, swizzled) ----
  hipMemsetAsync(mm, 0xFF, 4, stream);
  hipMemsetAsync(mm + 1, 0x00, 4, stream);
  fused2_k<<<NROWS / 64, 512, 0, stream>>>(x1b, rowstart, nbr, x0, agg0,
                                           Ws0, Wn0, wt, b1, b2, b3, g, mm);

  // ---- rescale + pooling ----
  hipMemsetAsync(pooled, 0, BB * 64 * sizeof(float), stream);
  pool2_k<<<(NN + 63) / 64, 256, 0, stream>>>(g, batch, mm, pooled);

  // ---- output linear ----
  out_k<<<BB, 64, 0, stream>>>(pooled, Wo, bo, out);
}